// Round 6
// baseline (843.625 us; speedup 1.0000x reference)
//
#include <hip/hip_runtime.h>
#include <hip/hip_bf16.h>

// Problem constants
#define NB     8
#define NPTS   4096
#define DIMC   64
#define KNN_K  8
#define NBLK   12
#define NREP   8      // stats replicas (atomic de-contention)
#define NWG    512    // blocks_kernel grid (2 WG/CU exactly; co-residency by capacity)

// ---------------------------------------------------------------------------
// Kernel 0: precompute (x, y, z, |x|^2) per point for the KNN kernel,
// PLUS zero all 13 stats stages and the 16 grid-barrier slots.
// ws is poisoned before every timed launch — re-zero every call; prep is
// stream-ordered before all consumers.
// sq formula matches numpy bit-for-bit (contract off, sequential adds).
// ---------------------------------------------------------------------------
__global__ __launch_bounds__(256) void prep_kernel(
        const float* __restrict__ xyz, float4* __restrict__ pts4g,
        float* __restrict__ stats, int* __restrict__ bar) {
#pragma clang fp contract(off)
    int g = blockIdx.x * 256 + threadIdx.x;      // 0..32767
    if (g < 13 * NREP * 128) stats[g] = 0.0f;
    if (g < 16) bar[g] = 0;
    int b = g >> 12, j = g & 4095;
    const float* xb = xyz + (size_t)b * 3 * NPTS;
    float x = xb[j];
    float y = xb[NPTS + j];
    float z = xb[2 * NPTS + j];
    float sq = (x * x + y * y) + z * z;
    pts4g[g] = make_float4(x, y, z, sq);
}

// ---------------------------------------------------------------------------
// Kernel 1: transpose fp32 points [b][d][n] -> point-major P0[b][n][d],
// fused with stats[0] accumulation. XCD-affine: b = blockIdx & 7.
// Grid: 512 WGs, 256 threads.
// ---------------------------------------------------------------------------
__global__ __launch_bounds__(256) void cast_kernel(
        const float* __restrict__ pts,
        float* __restrict__ P0, float* __restrict__ stats0) {
    __shared__ __align__(16) float tr[64 * 65];      // [d][n] transpose tile (+1 pad)
    __shared__ float slotA[4 * 64], slotB[4 * 64];
    int wg = blockIdx.x;
    int b = wg & 7;                  // XCD affinity
    int n0 = (wg >> 3) << 6;
    int rep = (wg >> 3) & (NREP - 1);
    int tid = threadIdx.x;
    int lane6 = tid & 63;
    int grp = tid >> 6;              // 0..3

    #pragma unroll
    for (int k = 0; k < 16; ++k) {
        int d = grp + (k << 2);
        float v = pts[(((size_t)((b << 6) + d)) << 12) + n0 + lane6];
        tr[d * 65 + lane6] = v;
    }
    __syncthreads();
    int c = lane6;
    float s = 0.0f, s2 = 0.0f;
    #pragma unroll
    for (int k = 0; k < 16; ++k) {
        int p = grp + (k << 2);
        float v = tr[c * 65 + p];
        P0[((size_t)((b << 12) + n0 + p)) * 64 + c] = v;
        s += v; s2 += v * v;
    }
    slotA[grp * 64 + c] = s;
    slotB[grp * 64 + c] = s2;
    __syncthreads();
    if (tid < 64) {
        float t = slotA[tid] + slotA[64 + tid] + slotA[128 + tid] + slotA[192 + tid];
        atomicAdd(&stats0[rep * 128 + tid], t);
    } else if (tid < 128) {
        int cc = tid - 64;
        float t = slotB[cc] + slotB[64 + cc] + slotB[128 + cc] + slotB[192 + cc];
        atomicAdd(&stats0[rep * 128 + 64 + cc], t);
    }
}

// ---------------------------------------------------------------------------
// Kernel 2: brute-force 8-NN, one query per lane, f64-key top-8.
// Scalar-fetch (R5, verified) + NEW 2-deep software pipeline of the
// s_load groups: R5 measured VALUBusy 66% — the compiler issued each
// group's 8 s_load_dwordx4 then stalled on lgkmcnt before the dots
// (~200 cyc SMEM latency vs ~112 cyc compute, 2 waves/SIMD can't hide).
// Now group j+1's loads are issued before group j is consumed, so the
// insert/drain VALU work covers the fetch.
// Exactness unchanged from verified R5: same scan order (chunk c scans
// contiguous [1024c,1024c+1024) ascending), same d2 formula (contract
// off), same unique-key construction (idx in low 12 mantissa bits,
// order-preserving, ties->lower idx), same gate (d2 < (float)k7, exact).
// Grid: 8 b x 32 q-tiles of 128 = 256 WGs, 512 threads.
// ---------------------------------------------------------------------------
#define INS(KEY) do { \
    double key = (KEY); \
    double n0 = fmin(k0, key); \
    double n1 = fmin(k1, fmax(k0, key)); \
    double n2 = fmin(k2, fmax(k1, key)); \
    double n3 = fmin(k3, fmax(k2, key)); \
    double n4 = fmin(k4, fmax(k3, key)); \
    double n5 = fmin(k5, fmax(k4, key)); \
    double n6 = fmin(k6, fmax(k5, key)); \
    double n7 = fmin(k7, fmax(k6, key)); \
    k0 = n0; k1 = n1; k2 = n2; k3 = n3; \
    k4 = n4; k5 = n5; k6 = n6; k7 = n7; } while (0)

__global__ __launch_bounds__(512) void knn_kernel(
        const float4* __restrict__ pts4g, int* __restrict__ idx) {
#pragma clang fp contract(off)
    __shared__ double stash[4 * 9 * 128];            // 36 KB (no cand staging)
    int wg = blockIdx.x;
    int b = wg >> 5;
    int q0 = (wg & 31) << 7;
    int tid = threadIdx.x;                           // 0..511

    int lane  = tid & 63;
    int wave  = tid >> 6;            // 0..7
    int chunk = wave & 3;
    int qgrp  = wave >> 2;           // 0..1
    int q_l   = (qgrp << 6) | lane;  // 0..127

    const float4* cb = pts4g + ((size_t)b << 12);
    float4 qp = cb[q0 + q_l];

    double k0, k1, k2, k3, k4, k5, k6, k7;
    k0 = k1 = k2 = k3 = k4 = k5 = k6 = k7 = __builtin_inf();
    float bd7f = 3.4e38f;

    // chunk is wave-uniform; readfirstlane makes it provable -> s_load.
    int chu = __builtin_amdgcn_readfirstlane(chunk);
    const float4* cc = cb + ((size_t)chu << 10);     // this wave's 1024-cand window
    int jg0 = chu << 10;                             // global candidate index base

    // prime the pipeline: group at jo=0
    float4 pc[8];
    #pragma unroll
    for (int u = 0; u < 8; ++u) pc[u] = cc[u];

    // --- direct phase: first 128 candidates, unconditional insert ---
    for (int jo = 0; jo < 128; jo += 8) {
        float4 pn[8];
        #pragma unroll
        for (int u = 0; u < 8; ++u) pn[u] = cc[jo + 8 + u];  // prefetch next (max idx 135)
        float d2v[8];
        #pragma unroll
        for (int u = 0; u < 8; ++u) {
            float dot = (qp.x * pc[u].x + qp.y * pc[u].y) + qp.z * pc[u].z;
            d2v[u] = (qp.w - 2.0f * dot) + pc[u].w;
        }
        #pragma unroll
        for (int u = 0; u < 8; ++u) {
            unsigned long long kb =
                __double_as_longlong((double)d2v[u]) |
                (unsigned long long)(jg0 + jo + u);
            INS(__longlong_as_double(kb));
        }
        #pragma unroll
        for (int u = 0; u < 8; ++u) pc[u] = pn[u];
    }
    bd7f = (float)k7;    // exact: idx bits << half-ulp of f32

    // --- queued phase: branchless hitmask + wave drain ---
    for (int jo = 128; jo < 1024; jo += 8) {
        float4 pn[8];
        if (jo + 8 < 1024) {
            #pragma unroll
            for (int u = 0; u < 8; ++u) pn[u] = cc[jo + 8 + u];
        }
        float d2v[8];
        unsigned hm = 0u;
        #pragma unroll
        for (int u = 0; u < 8; ++u) {
            float dot = (qp.x * pc[u].x + qp.y * pc[u].y) + qp.z * pc[u].z;
            float d2 = (qp.w - 2.0f * dot) + pc[u].w;
            d2v[u] = d2;
            hm |= (d2 < bd7f) ? (1u << u) : 0u;
        }
        while (__any(hm != 0u)) {
            if (hm) {
                int u = __builtin_ctz(hm);
                hm &= hm - 1u;
                // cndmask tree: d2 = d2v[u] with static indexing only
                float t0 = (u & 1) ? d2v[1] : d2v[0];
                float t1 = (u & 1) ? d2v[3] : d2v[2];
                float t2 = (u & 1) ? d2v[5] : d2v[4];
                float t3 = (u & 1) ? d2v[7] : d2v[6];
                float s0 = (u & 2) ? t1 : t0;
                float s1 = (u & 2) ? t3 : t2;
                float d2 = (u & 4) ? s1 : s0;
                unsigned long long kb =
                    __double_as_longlong((double)d2) |
                    (unsigned long long)(jg0 + jo + u);
                INS(__longlong_as_double(kb));
            }
        }
        bd7f = (float)k7;
        if (jo + 8 < 1024) {
            #pragma unroll
            for (int u = 0; u < 8; ++u) pc[u] = pn[u];
        }
    }

    {
        double* S = &stash[(chunk * 9) * 128 + q_l];
        S[0 * 128] = k0; S[1 * 128] = k1; S[2 * 128] = k2; S[3 * 128] = k3;
        S[4 * 128] = k4; S[5 * 128] = k5; S[6 * 128] = k6; S[7 * 128] = k7;
        S[8 * 128] = __builtin_inf();    // merge guard
    }
    __syncthreads();

    // 4-way merge per query by key (threads 0..127)
    if (tid < 128) {
        int h0 = 0, h1 = 0, h2 = 0, h3 = 0;
        int* op = idx + ((size_t)(b * NPTS + q0 + tid)) * 8;
        #pragma unroll
        for (int t = 0; t < 8; ++t) {
            double b0 = stash[(0 * 9 + h0) * 128 + tid];
            double b1 = stash[(1 * 9 + h1) * 128 + tid];
            double b2 = stash[(2 * 9 + h2) * 128 + tid];
            double b3 = stash[(3 * 9 + h3) * 128 + tid];
            double best = b0; int bc = 0;
            if (b1 < best) { best = b1; bc = 1; }
            if (b2 < best) { best = b2; bc = 2; }
            if (b3 < best) { best = b3; bc = 3; }
            h0 += (bc == 0); h1 += (bc == 1);
            h2 += (bc == 2); h3 += (bc == 3);
            op[t] = (int)(__double_as_longlong(best) & 0xFFFULL);
        }
    }
}

// ---------------------------------------------------------------------------
// Kernel 3: ALL 12 residual blocks in ONE kernel via a manual device-scope
// spin barrier (plain launch — graph-capturable, unlike
// hipLaunchCooperativeKernel, which is the likely cause of R3's silent
// no-op). Co-residency is guaranteed by capacity: 512 WGs x ~54.8 KB LDS
// = exactly 2 WG/CU, total capacity == grid size, so the dispatcher must
// place every WG (any unplaced WG implies a free slot somewhere).
// Barrier semantics: release = __threadfence() (L2 writeback is
// cache-wide, covers all WG threads' stores after __syncthreads) +
// agent-scope atomic arrive; acquire = agent-scope atomic spin +
// __threadfence() (cache-wide invalidate) + __syncthreads.
// Body is verbatim the verified R1 block (gather NOT pipelined — R5
// measured that variant slightly slower). idx tile loaded ONCE.
// Grid: 512 WGs (64 tiles x 8 b, XCD-affine b=wg&7), 256 threads.
// ---------------------------------------------------------------------------
__global__ __launch_bounds__(256) void blocks_kernel(
        float* __restrict__ P0, float* __restrict__ P1,
        float* __restrict__ stats,
        const float* __restrict__ conv_w, const float* __restrict__ conv_b,
        const float* __restrict__ gamma, const float* __restrict__ beta,
        const int* __restrict__ gidx, float* __restrict__ dout,
        int* __restrict__ bar) {
    __shared__ __align__(16) float Wt[64 * 68];      // W transposed: Wt[d][o]
    __shared__ __align__(16) float mt[64 * 68];      // m[d][pt]
    __shared__ __align__(16) float selft[64 * 64];   // raw self rows [pt][c]
    __shared__ __align__(16) int   idxl[64 * 8];
    __shared__ __align__(16) float scale_l[64], shift_l[64], bias_l[64];
    __shared__ float slot[4 * 128];

    int wg = blockIdx.x;
    int b = wg & 7;                  // XCD affinity
    int n0 = (wg >> 3) << 6;
    int rep = (wg >> 3) & (NREP - 1);
    int tid = threadIdx.x;

    // --- idx tile: invariant across all 12 blocks, load once ---
    if (tid < 128) {
        ((int4*)idxl)[tid] = ((const int4*)(gidx + ((size_t)(b * NPTS + n0)) * 8))[tid];
    }

    for (int t = 0; t < NBLK; ++t) {
        const float* Pin  = (t & 1) ? P1 : P0;
        float*       Pout = (t & 1) ? P0 : P1;
        const float* statsIn  = stats + (size_t)t * NREP * 128;
        float*       statsOut = stats + (size_t)(t + 1) * NREP * 128;
        const float* Wp    = conv_w + (size_t)t * 4096;
        const float* Bp    = conv_b + (size_t)t * 64;
        const float* Gp    = gamma  + (size_t)t * 64;
        const float* Betap = beta   + (size_t)t * 64;
        int last = (t == NBLK - 1);

        const float* Pb = Pin + (((size_t)b) << 18);     // batch slice [4096][64]

        // --- setup: self tile, W^T, BN affine (replica-summed) ---
        #pragma unroll
        for (int k = 0; k < 4; ++k) {    // self rows: 64 pts x 64 ch, coalesced
            int lin = tid + (k << 8);    // float4 id
            ((float4*)selft)[lin] = ((const float4*)&Pb[(size_t)n0 << 6])[lin];
        }
        #pragma unroll
        for (int k = 0; k < 16; ++k) {
            int lin = tid + (k << 8);
            int o = lin >> 6, d = lin & 63;
            Wt[d * 68 + o] = Wp[lin];
        }
        if (tid < 64) {
            int c = tid;
            float sum = 0.0f, sumsq = 0.0f;
            #pragma unroll
            for (int r = 0; r < NREP; ++r) {
                sum   += statsIn[r * 128 + c];
                sumsq += statsIn[r * 128 + 64 + c];
            }
            float mean = sum * (1.0f / 32768.0f);
            float var  = sumsq * (1.0f / 32768.0f) - mean * mean;
            float rs   = 1.0f / sqrtf(var + 1e-5f);
            float sc   = Gp[c] * rs;
            scale_l[c] = sc;
            shift_l[c] = Betap[c] - mean * sc;
            bias_l[c]  = Bp[c];
        }
        __syncthreads();

        // --- gather: m[d][pt]; self from LDS, 8 neighbors from (local-L2) global ---
        {
            int cq = tid & 15;           // channel quad: channels 4cq..4cq+3
            int pg = tid >> 4;           // 0..15: points 4pg..4pg+3
            int c4 = cq << 2;
            float4 sc4 = *(const float4*)&scale_l[c4];
            float4 sh4 = *(const float4*)&shift_l[c4];
            #pragma unroll
            for (int i = 0; i < 4; ++i) {
                int pt = (pg << 2) + i;
                int4 ja = *(const int4*)&idxl[pt * 8];
                int4 jb = *(const int4*)&idxl[pt * 8 + 4];
                float4 v[9];
                v[0] = *(const float4*)&selft[(pt << 6) + c4];
                v[1] = *(const float4*)&Pb[(((size_t)ja.x) << 6) + c4];
                v[2] = *(const float4*)&Pb[(((size_t)ja.y) << 6) + c4];
                v[3] = *(const float4*)&Pb[(((size_t)ja.z) << 6) + c4];
                v[4] = *(const float4*)&Pb[(((size_t)ja.w) << 6) + c4];
                v[5] = *(const float4*)&Pb[(((size_t)jb.x) << 6) + c4];
                v[6] = *(const float4*)&Pb[(((size_t)jb.y) << 6) + c4];
                v[7] = *(const float4*)&Pb[(((size_t)jb.z) << 6) + c4];
                v[8] = *(const float4*)&Pb[(((size_t)jb.w) << 6) + c4];
                float4 a = make_float4(0.f, 0.f, 0.f, 0.f);
                #pragma unroll
                for (int k = 0; k < 9; ++k) {
                    float hx = v[k].x * sc4.x + sh4.x;
                    float hy = v[k].y * sc4.y + sh4.y;
                    float hz = v[k].z * sc4.z + sh4.z;
                    float hw = v[k].w * sc4.w + sh4.w;
                    a.x += fmaxf(hx, 0.01f * hx);
                    a.y += fmaxf(hy, 0.01f * hy);
                    a.z += fmaxf(hz, 0.01f * hz);
                    a.w += fmaxf(hw, 0.01f * hw);
                }
                mt[(c4 + 0) * 68 + pt] = a.x * (1.0f / 9.0f);
                mt[(c4 + 1) * 68 + pt] = a.y * (1.0f / 9.0f);
                mt[(c4 + 2) * 68 + pt] = a.z * (1.0f / 9.0f);
                mt[(c4 + 3) * 68 + pt] = a.w * (1.0f / 9.0f);
            }
        }
        __syncthreads();

        // --- GEMM: out[pt][o] = sum_d Wt[d][o] * m[d][pt] + bias[o] ---
        int o0 = (tid & 15) << 2;
        int p0 = (tid >> 4) << 2;
        float4 acc[4];
        {
            float4 bias4 = *(const float4*)&bias_l[o0];
            acc[0] = bias4; acc[1] = bias4; acc[2] = bias4; acc[3] = bias4;
        }
        #pragma unroll
        for (int d = 0; d < 64; ++d) {
            float4 wv = *(const float4*)&Wt[d * 68 + o0];
            float4 a  = *(const float4*)&mt[d * 68 + p0];
            acc[0].x += wv.x * a.x; acc[0].y += wv.y * a.x; acc[0].z += wv.z * a.x; acc[0].w += wv.w * a.x;
            acc[1].x += wv.x * a.y; acc[1].y += wv.y * a.y; acc[1].z += wv.z * a.y; acc[1].w += wv.w * a.y;
            acc[2].x += wv.x * a.z; acc[2].y += wv.y * a.z; acc[2].z += wv.z * a.z; acc[2].w += wv.w * a.z;
            acc[3].x += wv.x * a.w; acc[3].y += wv.y * a.w; acc[3].z += wv.z * a.w; acc[3].w += wv.w * a.w;
        }

        // --- residual add (self rows from LDS) ---
        #pragma unroll
        for (int j = 0; j < 4; ++j) {
            float4 r = *(const float4*)&selft[((p0 + j) << 6) + o0];
            acc[j].x += r.x; acc[j].y += r.y; acc[j].z += r.z; acc[j].w += r.w;
        }

        if (!last) {
            float* PbOut = Pout + ((((size_t)b) << 12) + n0) * 64;
            #pragma unroll
            for (int j = 0; j < 4; ++j)
                *(float4*)&PbOut[((size_t)(p0 + j)) * 64 + o0] = acc[j];

            float4 s, s2;
            s.x = acc[0].x + acc[1].x + acc[2].x + acc[3].x;
            s.y = acc[0].y + acc[1].y + acc[2].y + acc[3].y;
            s.z = acc[0].z + acc[1].z + acc[2].z + acc[3].z;
            s.w = acc[0].w + acc[1].w + acc[2].w + acc[3].w;
            s2.x = acc[0].x*acc[0].x + acc[1].x*acc[1].x + acc[2].x*acc[2].x + acc[3].x*acc[3].x;
            s2.y = acc[0].y*acc[0].y + acc[1].y*acc[1].y + acc[2].y*acc[2].y + acc[3].y*acc[3].y;
            s2.z = acc[0].z*acc[0].z + acc[1].z*acc[1].z + acc[2].z*acc[2].z + acc[3].z*acc[3].z;
            s2.w = acc[0].w*acc[0].w + acc[1].w*acc[1].w + acc[2].w*acc[2].w + acc[3].w*acc[3].w;
            #pragma unroll
            for (int m = 16; m <= 32; m <<= 1) {
                s.x += __shfl_xor(s.x, m, 64);  s.y += __shfl_xor(s.y, m, 64);
                s.z += __shfl_xor(s.z, m, 64);  s.w += __shfl_xor(s.w, m, 64);
                s2.x += __shfl_xor(s2.x, m, 64); s2.y += __shfl_xor(s2.y, m, 64);
                s2.z += __shfl_xor(s2.z, m, 64); s2.w += __shfl_xor(s2.w, m, 64);
            }
            if ((tid & 63) < 16) {
                int w = tid >> 6;
                slot[w * 128 + o0 + 0] = s.x;  slot[w * 128 + o0 + 1] = s.y;
                slot[w * 128 + o0 + 2] = s.z;  slot[w * 128 + o0 + 3] = s.w;
                slot[w * 128 + 64 + o0 + 0] = s2.x; slot[w * 128 + 64 + o0 + 1] = s2.y;
                slot[w * 128 + 64 + o0 + 2] = s2.z; slot[w * 128 + 64 + o0 + 3] = s2.w;
            }
            __syncthreads();
            if (tid < 128) {
                float tt = slot[tid] + slot[128 + tid] + slot[256 + tid] + slot[384 + tid];
                atomicAdd(&statsOut[rep * 128 + tid], tt);
            }

            // ---- device-wide barrier: P_out + stats of block t visible ----
            __syncthreads();                 // all WG threads' stores/atomics issued
            if (tid == 0) {
                __threadfence();             // release: cache-wide L2 writeback
                int a = __hip_atomic_fetch_add(&bar[t], 1,
                            __ATOMIC_ACQ_REL, __HIP_MEMORY_SCOPE_AGENT);
                if (a + 1 < NWG) {
                    while (__hip_atomic_load(&bar[t],
                                __ATOMIC_ACQUIRE, __HIP_MEMORY_SCOPE_AGENT) < NWG)
                        __builtin_amdgcn_s_sleep(1);
                }
                __threadfence();             // acquire: cache-wide invalidate
            }
            __syncthreads();
        } else {
            __syncthreads();                         // all mt reads done
            float* stage = mt;                       // reuse as [o][pt], 16 KB
            #pragma unroll
            for (int j = 0; j < 4; ++j) {
                stage[(o0 + 0) * 64 + p0 + j] = acc[j].x;
                stage[(o0 + 1) * 64 + p0 + j] = acc[j].y;
                stage[(o0 + 2) * 64 + p0 + j] = acc[j].z;
                stage[(o0 + 3) * 64 + p0 + j] = acc[j].w;
            }
            __syncthreads();
            #pragma unroll
            for (int k = 0; k < 16; ++k) {
                int lin = tid + (k << 8);
                int o = lin >> 6, pt = lin & 63;
                dout[(((size_t)((b << 6) + o)) << 12) + n0 + pt] = stage[lin];
            }
        }
    }
}

// ---------------------------------------------------------------------------
extern "C" void kernel_launch(void* const* d_in, const int* in_sizes, int n_in,
                              void* d_out, int out_size, void* d_ws, size_t ws_size,
                              hipStream_t stream) {
    const float* xyz    = (const float*)d_in[0];
    const float* pts    = (const float*)d_in[1];
    const float* conv_w = (const float*)d_in[2];
    const float* conv_b = (const float*)d_in[3];
    const float* gamma  = (const float*)d_in[4];
    const float* beta   = (const float*)d_in[5];
    float* out = (float*)d_out;

    char* ws = (char*)d_ws;
    float*  P0    = (float*)(ws);                                  //  8 MB
    float*  P1    = (float*)(ws + (size_t)8 * 1024 * 1024);        //  8 MB
    int*    idx   = (int*)  (ws + (size_t)16 * 1024 * 1024);       //  1 MB
    float*  stats = (float*)(ws + (size_t)17 * 1024 * 1024);       // 52 KB
    int*    bar   = (int*)  (ws + (size_t)17 * 1024 * 1024 + 64 * 1024);  // 64 B
    float4* pts4g = (float4*)(ws + (size_t)18 * 1024 * 1024);      // 512 KB

    prep_kernel<<<128, 256, 0, stream>>>(xyz, pts4g, stats, bar);
    cast_kernel<<<512, 256, 0, stream>>>(pts, P0, stats);
    knn_kernel<<<256, 512, 0, stream>>>(pts4g, idx);

    blocks_kernel<<<NWG, 256, 0, stream>>>(
        P0, P1, stats, conv_w, conv_b, gamma, beta, idx, out, bar);
}

// Round 7
// 347.729 us; speedup vs baseline: 2.4261x; 2.4261x over previous
//
#include <hip/hip_runtime.h>
#include <hip/hip_bf16.h>

// Problem constants
#define NB     8
#define NPTS   4096
#define DIMC   64
#define KNN_K  8
#define NBLK   12
#define NREP   8      // stats replicas (atomic de-contention)

// ---------------------------------------------------------------------------
// Kernel 0: precompute (x, y, z, |x|^2) per point for the KNN kernel,
// zero all 13 stats stages, AND transpose the 12 conv weights
// WtG[t][d][o] = W[t][o][d] (enables wave-uniform scalar s_load of W rows
// in the block GEMM). 192 WGs x 256 = 49152 threads covers all three.
// sq formula matches numpy bit-for-bit (contract off, sequential adds).
// ---------------------------------------------------------------------------
__global__ __launch_bounds__(256) void prep_kernel(
        const float* __restrict__ xyz, float4* __restrict__ pts4g,
        float* __restrict__ stats, const float* __restrict__ conv_w,
        float* __restrict__ wtg) {
#pragma clang fp contract(off)
    int g = blockIdx.x * 256 + threadIdx.x;      // 0..49151
    if (g < 13 * NREP * 128) stats[g] = 0.0f;
    if (g < NBLK * 4096) {                       // W transpose (reads coalesced)
        int t = g >> 12, rem = g & 4095;
        int o = rem >> 6, d = rem & 63;
        wtg[(t << 12) + (d << 6) + o] = conv_w[g];
    }
    if (g < 32768) {
        int b = g >> 12, j = g & 4095;
        const float* xb = xyz + (size_t)b * 3 * NPTS;
        float x = xb[j];
        float y = xb[NPTS + j];
        float z = xb[2 * NPTS + j];
        float sq = (x * x + y * y) + z * z;
        pts4g[g] = make_float4(x, y, z, sq);
    }
}

// ---------------------------------------------------------------------------
// Kernel 1: transpose fp32 points [b][d][n] -> point-major P0[b][n][d],
// fused with stats[0] accumulation. XCD-affine: b = blockIdx & 7.
// Grid: 512 WGs, 256 threads.
// ---------------------------------------------------------------------------
__global__ __launch_bounds__(256) void cast_kernel(
        const float* __restrict__ pts,
        float* __restrict__ P0, float* __restrict__ stats0) {
    __shared__ __align__(16) float tr[64 * 65];      // [d][n] transpose tile (+1 pad)
    __shared__ float slotA[4 * 64], slotB[4 * 64];
    int wg = blockIdx.x;
    int b = wg & 7;                  // XCD affinity
    int n0 = (wg >> 3) << 6;
    int rep = (wg >> 3) & (NREP - 1);
    int tid = threadIdx.x;
    int lane6 = tid & 63;
    int grp = tid >> 6;              // 0..3

    #pragma unroll
    for (int k = 0; k < 16; ++k) {
        int d = grp + (k << 2);
        float v = pts[(((size_t)((b << 6) + d)) << 12) + n0 + lane6];
        tr[d * 65 + lane6] = v;
    }
    __syncthreads();
    int c = lane6;
    float s = 0.0f, s2 = 0.0f;
    #pragma unroll
    for (int k = 0; k < 16; ++k) {
        int p = grp + (k << 2);
        float v = tr[c * 65 + p];
        P0[((size_t)((b << 12) + n0 + p)) * 64 + c] = v;
        s += v; s2 += v * v;
    }
    slotA[grp * 64 + c] = s;
    slotB[grp * 64 + c] = s2;
    __syncthreads();
    if (tid < 64) {
        float t = slotA[tid] + slotA[64 + tid] + slotA[128 + tid] + slotA[192 + tid];
        atomicAdd(&stats0[rep * 128 + tid], t);
    } else if (tid < 128) {
        int cc = tid - 64;
        float t = slotB[cc] + slotB[64 + cc] + slotB[128 + cc] + slotB[192 + cc];
        atomicAdd(&stats0[rep * 128 + 64 + cc], t);
    }
}

// ---------------------------------------------------------------------------
// Kernel 2: brute-force 8-NN — EXACT R5 form (measured 111.4 us, verified).
// R6's 2-deep prefetch pipeline regressed (~145 us, likely SGPR spill) and
// is reverted. Scalar-fetch: chunk base wave-uniform via readfirstlane ->
// s_load; no LDS candidate staging.
// Exactness: chunk c scans contiguous [1024c,1024c+1024) ascending; keys
// unique (idx in low 12 mantissa bits, order-preserving, ties->lower idx);
// d2 formula matches numpy bit-for-bit (contract off); gate d2<(float)k7
// exact. Insert chain n_i = fmin(k_i, fmax(k_{i-1}, key)) reads only OLD
// k values -> dependency depth 2, already parallel.
// Grid: 8 b x 32 q-tiles of 128 = 256 WGs, 512 threads.
// ---------------------------------------------------------------------------
#define INS(KEY) do { \
    double key = (KEY); \
    double n0 = fmin(k0, key); \
    double n1 = fmin(k1, fmax(k0, key)); \
    double n2 = fmin(k2, fmax(k1, key)); \
    double n3 = fmin(k3, fmax(k2, key)); \
    double n4 = fmin(k4, fmax(k3, key)); \
    double n5 = fmin(k5, fmax(k4, key)); \
    double n6 = fmin(k6, fmax(k5, key)); \
    double n7 = fmin(k7, fmax(k6, key)); \
    k0 = n0; k1 = n1; k2 = n2; k3 = n3; \
    k4 = n4; k5 = n5; k6 = n6; k7 = n7; } while (0)

__global__ __launch_bounds__(512) void knn_kernel(
        const float4* __restrict__ pts4g, int* __restrict__ idx) {
#pragma clang fp contract(off)
    __shared__ double stash[4 * 9 * 128];            // 36 KB (no cand staging)
    int wg = blockIdx.x;
    int b = wg >> 5;
    int q0 = (wg & 31) << 7;
    int tid = threadIdx.x;                           // 0..511

    int lane  = tid & 63;
    int wave  = tid >> 6;            // 0..7
    int chunk = wave & 3;
    int qgrp  = wave >> 2;           // 0..1
    int q_l   = (qgrp << 6) | lane;  // 0..127

    const float4* cb = pts4g + ((size_t)b << 12);
    float4 qp = cb[q0 + q_l];

    double k0, k1, k2, k3, k4, k5, k6, k7;
    k0 = k1 = k2 = k3 = k4 = k5 = k6 = k7 = __builtin_inf();
    float bd7f = 3.4e38f;

    int chu = __builtin_amdgcn_readfirstlane(chunk);
    const float4* cc = cb + ((size_t)chu << 10);     // this wave's 1024-cand window
    int jg0 = chu << 10;                             // global candidate index base

    // --- direct phase: first 128 candidates of the chunk, unconditional ---
    for (int jo = 0; jo < 128; jo += 8) {
        float d2v[8];
        #pragma unroll
        for (int u = 0; u < 8; ++u) {
            float4 p = cc[jo + u];                   // uniform -> s_load
            float dot = (qp.x * p.x + qp.y * p.y) + qp.z * p.z;
            d2v[u] = (qp.w - 2.0f * dot) + p.w;
        }
        #pragma unroll
        for (int u = 0; u < 8; ++u) {
            unsigned long long kb =
                __double_as_longlong((double)d2v[u]) |
                (unsigned long long)(jg0 + jo + u);
            INS(__longlong_as_double(kb));
        }
    }
    bd7f = (float)k7;    // exact: idx bits << half-ulp of f32

    // --- queued phase: branchless hitmask + wave drain ---
    for (int jo = 128; jo < 1024; jo += 8) {
        float d2v[8];
        unsigned hm = 0u;
        #pragma unroll
        for (int u = 0; u < 8; ++u) {
            float4 p = cc[jo + u];                   // uniform -> s_load
            float dot = (qp.x * p.x + qp.y * p.y) + qp.z * p.z;
            float d2 = (qp.w - 2.0f * dot) + p.w;
            d2v[u] = d2;
            hm |= (d2 < bd7f) ? (1u << u) : 0u;
        }
        while (__any(hm != 0u)) {
            if (hm) {
                int u = __builtin_ctz(hm);
                hm &= hm - 1u;
                // cndmask tree: d2 = d2v[u] with static indexing only
                float t0 = (u & 1) ? d2v[1] : d2v[0];
                float t1 = (u & 1) ? d2v[3] : d2v[2];
                float t2 = (u & 1) ? d2v[5] : d2v[4];
                float t3 = (u & 1) ? d2v[7] : d2v[6];
                float s0 = (u & 2) ? t1 : t0;
                float s1 = (u & 2) ? t3 : t2;
                float d2 = (u & 4) ? s1 : s0;
                unsigned long long kb =
                    __double_as_longlong((double)d2) |
                    (unsigned long long)(jg0 + jo + u);
                INS(__longlong_as_double(kb));
            }
        }
        bd7f = (float)k7;
    }

    {
        double* S = &stash[(chunk * 9) * 128 + q_l];
        S[0 * 128] = k0; S[1 * 128] = k1; S[2 * 128] = k2; S[3 * 128] = k3;
        S[4 * 128] = k4; S[5 * 128] = k5; S[6 * 128] = k6; S[7 * 128] = k7;
        S[8 * 128] = __builtin_inf();    // merge guard
    }
    __syncthreads();

    // 4-way merge per query by key (threads 0..127)
    if (tid < 128) {
        int h0 = 0, h1 = 0, h2 = 0, h3 = 0;
        int* op = idx + ((size_t)(b * NPTS + q0 + tid)) * 8;
        #pragma unroll
        for (int t = 0; t < 8; ++t) {
            double b0 = stash[(0 * 9 + h0) * 128 + tid];
            double b1 = stash[(1 * 9 + h1) * 128 + tid];
            double b2 = stash[(2 * 9 + h2) * 128 + tid];
            double b3 = stash[(3 * 9 + h3) * 128 + tid];
            double best = b0; int bc = 0;
            if (b1 < best) { best = b1; bc = 1; }
            if (b2 < best) { best = b2; bc = 2; }
            if (b3 < best) { best = b3; bc = 3; }
            h0 += (bc == 0); h1 += (bc == 1);
            h2 += (bc == 2); h3 += (bc == 3);
            op[t] = (int)(__double_as_longlong(best) & 0xFFFULL);
        }
    }
}

// ---------------------------------------------------------------------------
// Kernel 3 (x12): one residual block. GEMM RESTRUCTURED:
//   - one point per lane, 16 output channels per wave (o-range made
//     wave-uniform via readfirstlane) -> W rows are wave-uniform ->
//     SCALAR s_load from pre-transposed WtG[d][o] (off VALU + LDS pipes).
//   - per-lane m-row read: 16 ds_read_b128/thread instead of 128 (8x
//     fewer LDS-pipe instructions; old floor ~5.1 us/block/CU).
//   - selft/mt use a ROTATED row layout: float4 slot s = (d4 + pt) & 15.
//     Per-lane row reads then hit 8 distinct bank-quads (conflict-free
//     floor) while the CONSUMED d stays uniform per instruction (an XOR
//     swizzle would break W's wave-uniformity; rotation doesn't).
//     Gather's mt write becomes one b128 (was 4x b32, 8-way conflicted:
//     590K conflicts/block measured in R6).
//   - d-accumulation order unchanged (ascending d; bias first, residual
//     after) -> GEMM output bit-identical to the verified R5 kernel.
//   - last block: lane owns [pt][ob..ob+15] -> dout writes are directly
//     coalesced over n; LDS transpose stage deleted.
// Grid: 512 WGs (64 tiles x 8 b, XCD-affine b = wg & 7), 256 threads.
// LDS ~35 KB.
// ---------------------------------------------------------------------------
__global__ __launch_bounds__(256) void block_kernel(
        const float* __restrict__ Pin, float* __restrict__ Pout,
        const float* __restrict__ statsIn, float* __restrict__ statsOut,
        const float* __restrict__ Wq,    // transposed weights [d][o]
        const float* __restrict__ Bp,
        const float* __restrict__ Gp, const float* __restrict__ Betap,
        const int* __restrict__ gidx, float* __restrict__ dout, int last) {
    __shared__ __align__(16) float selft[64 * 64];   // raw self rows, rotated
    __shared__ __align__(16) float mt[64 * 64];      // m rows, rotated; stats stage
    __shared__ __align__(16) int   idxl[64 * 8];
    __shared__ __align__(16) float scale_l[64], shift_l[64], bias_l[64];

    int wg = blockIdx.x;
    int b = wg & 7;                  // XCD affinity
    int n0 = (wg >> 3) << 6;
    int rep = (wg >> 3) & (NREP - 1);
    int tid = threadIdx.x;

    const float* Pb = Pin + (((size_t)b) << 18);     // batch slice [4096][64]

    // --- setup: idx tile, self tile (rotated), BN affine ---
    if (tid < 128) {
        ((int4*)idxl)[tid] = ((const int4*)(gidx + ((size_t)(b * NPTS + n0)) * 8))[tid];
    }
    {
        const float4* src = (const float4*)&Pb[(size_t)n0 << 6];
        float4* dst = (float4*)selft;
        #pragma unroll
        for (int k = 0; k < 4; ++k) {
            int lin = tid + (k << 8);                // float4 id 0..1023
            int pt = lin >> 4, d4 = lin & 15;
            dst[(pt << 4) + ((d4 + pt) & 15)] = src[lin];
        }
    }
    if (tid < 64) {
        int c = tid;
        float sum = 0.0f, sumsq = 0.0f;
        #pragma unroll
        for (int r = 0; r < NREP; ++r) {
            sum   += statsIn[r * 128 + c];
            sumsq += statsIn[r * 128 + 64 + c];
        }
        float mean = sum * (1.0f / 32768.0f);
        float var  = sumsq * (1.0f / 32768.0f) - mean * mean;
        float rs   = 1.0f / sqrtf(var + 1e-5f);
        float sc   = Gp[c] * rs;
        scale_l[c] = sc;
        shift_l[c] = Betap[c] - mean * sc;
        bias_l[c]  = Bp[c];
    }
    __syncthreads();

    // --- gather: m[pt][c4..c4+3] -> rotated slot; one b128 write ---
    {
        int cq = tid & 15;           // channel quad
        int pg = tid >> 4;           // point group
        int c4 = cq << 2;
        float4 sc4 = *(const float4*)&scale_l[c4];
        float4 sh4 = *(const float4*)&shift_l[c4];
        #pragma unroll
        for (int i = 0; i < 4; ++i) {
            int pt = (pg << 2) + i;
            int4 ja = *(const int4*)&idxl[pt * 8];
            int4 jb = *(const int4*)&idxl[pt * 8 + 4];
            float4 v[9];
            v[0] = ((const float4*)selft)[(pt << 4) + ((cq + pt) & 15)];
            v[1] = *(const float4*)&Pb[(((size_t)ja.x) << 6) + c4];
            v[2] = *(const float4*)&Pb[(((size_t)ja.y) << 6) + c4];
            v[3] = *(const float4*)&Pb[(((size_t)ja.z) << 6) + c4];
            v[4] = *(const float4*)&Pb[(((size_t)ja.w) << 6) + c4];
            v[5] = *(const float4*)&Pb[(((size_t)jb.x) << 6) + c4];
            v[6] = *(const float4*)&Pb[(((size_t)jb.y) << 6) + c4];
            v[7] = *(const float4*)&Pb[(((size_t)jb.z) << 6) + c4];
            v[8] = *(const float4*)&Pb[(((size_t)jb.w) << 6) + c4];
            float4 a = make_float4(0.f, 0.f, 0.f, 0.f);
            #pragma unroll
            for (int k = 0; k < 9; ++k) {
                float hx = v[k].x * sc4.x + sh4.x;
                float hy = v[k].y * sc4.y + sh4.y;
                float hz = v[k].z * sc4.z + sh4.z;
                float hw = v[k].w * sc4.w + sh4.w;
                a.x += fmaxf(hx, 0.01f * hx);
                a.y += fmaxf(hy, 0.01f * hy);
                a.z += fmaxf(hz, 0.01f * hz);
                a.w += fmaxf(hw, 0.01f * hw);
            }
            float4 m4 = make_float4(a.x * (1.0f / 9.0f), a.y * (1.0f / 9.0f),
                                    a.z * (1.0f / 9.0f), a.w * (1.0f / 9.0f));
            ((float4*)mt)[(pt << 4) + ((cq + pt) & 15)] = m4;
        }
    }
    __syncthreads();

    // --- GEMM: lane = point, wave = 16-channel slab, W via scalar loads ---
    int lane = tid & 63;
    int wvi  = tid >> 6;                                     // 0..3
    int ob   = __builtin_amdgcn_readfirstlane(wvi) << 4;     // wave-uniform
    float acc[16];
    #pragma unroll
    for (int j = 0; j < 4; ++j) {
        float4 bb = *(const float4*)&bias_l[ob + (j << 2)];  // uniform -> broadcast
        acc[j * 4 + 0] = bb.x; acc[j * 4 + 1] = bb.y;
        acc[j * 4 + 2] = bb.z; acc[j * 4 + 3] = bb.w;
    }
    {
        const float4* mv = (const float4*)mt;
        #pragma unroll
        for (int k = 0; k < 16; ++k) {
            float4 a4 = mv[(lane << 4) + ((k + lane) & 15)]; // m[lane][4k..4k+3]
            const float* wr = Wq + (k << 8) + ob;            // W rows 4k..4k+3, cols ob..
            #pragma unroll
            for (int j = 0; j < 16; ++j) acc[j] += wr[j] * a4.x;
            #pragma unroll
            for (int j = 0; j < 16; ++j) acc[j] += wr[64 + j] * a4.y;
            #pragma unroll
            for (int j = 0; j < 16; ++j) acc[j] += wr[128 + j] * a4.z;
            #pragma unroll
            for (int j = 0; j < 16; ++j) acc[j] += wr[192 + j] * a4.w;
        }
    }

    // --- residual add (self row, rotated slots) ---
    #pragma unroll
    for (int j = 0; j < 4; ++j) {
        float4 r4 = ((const float4*)selft)[(lane << 4) + (((ob >> 2) + j + lane) & 15)];
        acc[j * 4 + 0] += r4.x; acc[j * 4 + 1] += r4.y;
        acc[j * 4 + 2] += r4.z; acc[j * 4 + 3] += r4.w;
    }

    if (!last) {
        float* PbOut = Pout + ((((size_t)b) << 12) + n0) * 64;
        #pragma unroll
        for (int j = 0; j < 4; ++j) {
            *(float4*)&PbOut[(size_t)lane * 64 + ob + (j << 2)] =
                make_float4(acc[j * 4 + 0], acc[j * 4 + 1],
                            acc[j * 4 + 2], acc[j * 4 + 3]);
        }

        // --- stats: per-lane values, butterfly over pts, LDS stage, atomics ---
        float sv[16], qv[16];
        #pragma unroll
        for (int j = 0; j < 16; ++j) { sv[j] = acc[j]; qv[j] = acc[j] * acc[j]; }
        #pragma unroll
        for (int m = 16; m <= 32; m <<= 1) {
            #pragma unroll
            for (int j = 0; j < 16; ++j) {
                sv[j] += __shfl_xor(sv[j], m, 64);
                qv[j] += __shfl_xor(qv[j], m, 64);
            }
        }
        __syncthreads();                 // all GEMM mt reads complete
        float* stage = mt;               // reuse: [4 waves][16 lanes][32]
        if (lane < 16) {
            int base = ((wvi << 4) + lane) << 5;
            #pragma unroll
            for (int j = 0; j < 16; ++j) stage[base + j] = sv[j];
            #pragma unroll
            for (int j = 0; j < 16; ++j) stage[base + 16 + j] = qv[j];
        }
        __syncthreads();
        if (tid < 128) {
            int c = tid & 63, isq = tid >> 6;
            int w = c >> 4, j = c & 15;
            float s = 0.0f;
            #pragma unroll
            for (int l = 0; l < 16; ++l)
                s += stage[(((w << 4) + l) << 5) + (isq << 4) + j];
            atomicAdd(&statsOut[rep * 128 + (isq << 6) + c], s);
        }
    } else {
        // lane owns [pt=lane][ob..ob+15] -> coalesced over n, no staging
        #pragma unroll
        for (int j = 0; j < 16; ++j)
            dout[(((size_t)((b << 6) + ob + j)) << 12) + n0 + lane] = acc[j];
    }
}

// ---------------------------------------------------------------------------
extern "C" void kernel_launch(void* const* d_in, const int* in_sizes, int n_in,
                              void* d_out, int out_size, void* d_ws, size_t ws_size,
                              hipStream_t stream) {
    const float* xyz    = (const float*)d_in[0];
    const float* pts    = (const float*)d_in[1];
    const float* conv_w = (const float*)d_in[2];
    const float* conv_b = (const float*)d_in[3];
    const float* gamma  = (const float*)d_in[4];
    const float* beta   = (const float*)d_in[5];
    float* out = (float*)d_out;

    char* ws = (char*)d_ws;
    float*  P0    = (float*)(ws);                                  //  8 MB
    float*  P1    = (float*)(ws + (size_t)8 * 1024 * 1024);        //  8 MB
    int*    idx   = (int*)  (ws + (size_t)16 * 1024 * 1024);       //  1 MB
    float*  stats = (float*)(ws + (size_t)17 * 1024 * 1024);       // 52 KB
    float*  wtg   = (float*)(ws + (size_t)17 * 1024 * 1024 + 128 * 1024); // 192 KB
    float4* pts4g = (float4*)(ws + (size_t)18 * 1024 * 1024);      // 512 KB

    prep_kernel<<<192, 256, 0, stream>>>(xyz, pts4g, stats, conv_w, wtg);
    cast_kernel<<<512, 256, 0, stream>>>(pts, P0, stats);
    knn_kernel<<<256, 512, 0, stream>>>(pts4g, idx);

    float* Pbuf[2] = {P0, P1};
    for (int t = 0; t < NBLK; ++t) {
        block_kernel<<<512, 256, 0, stream>>>(
            Pbuf[t & 1], Pbuf[(t + 1) & 1],
            stats + (size_t)t * NREP * 128, stats + (size_t)(t + 1) * NREP * 128,
            wtg + (size_t)t * 4096, conv_b + (size_t)t * 64,
            gamma + (size_t)t * 64, beta + (size_t)t * 64,
            idx, out, (t == NBLK - 1) ? 1 : 0);
    }
}

// Round 8
// 309.129 us; speedup vs baseline: 2.7290x; 1.1249x over previous
//
#include <hip/hip_runtime.h>
#include <hip/hip_bf16.h>

// Problem constants
#define NB     8
#define NPTS   4096
#define DIMC   64
#define KNN_K  8
#define NBLK   12
#define NREP   8      // stats replicas (atomic de-contention)

// ---------------------------------------------------------------------------
// Kernel 0: precompute (x, y, z, |x|^2) per point for the KNN kernel,
// PLUS zero all 13 stats stages (13*8*128 = 13312 floats <= 32768 threads).
// sq formula matches numpy bit-for-bit (contract off, sequential adds).
// ---------------------------------------------------------------------------
__global__ __launch_bounds__(256) void prep_kernel(
        const float* __restrict__ xyz, float4* __restrict__ pts4g,
        float* __restrict__ stats) {
#pragma clang fp contract(off)
    int g = blockIdx.x * 256 + threadIdx.x;      // 0..32767
    if (g < 13 * NREP * 128) stats[g] = 0.0f;
    int b = g >> 12, j = g & 4095;
    const float* xb = xyz + (size_t)b * 3 * NPTS;
    float x = xb[j];
    float y = xb[NPTS + j];
    float z = xb[2 * NPTS + j];
    float sq = (x * x + y * y) + z * z;
    pts4g[g] = make_float4(x, y, z, sq);
}

// ---------------------------------------------------------------------------
// Kernel 1: transpose fp32 points [b][d][n] -> point-major P0[b][n][d],
// fused with stats[0] accumulation. XCD-affine: b = blockIdx & 7.
// Grid: 512 WGs, 256 threads.
// ---------------------------------------------------------------------------
__global__ __launch_bounds__(256) void cast_kernel(
        const float* __restrict__ pts,
        float* __restrict__ P0, float* __restrict__ stats0) {
    __shared__ __align__(16) float tr[64 * 65];      // [d][n] transpose tile (+1 pad)
    __shared__ float slotA[4 * 64], slotB[4 * 64];
    int wg = blockIdx.x;
    int b = wg & 7;                  // XCD affinity
    int n0 = (wg >> 3) << 6;
    int rep = (wg >> 3) & (NREP - 1);
    int tid = threadIdx.x;
    int lane6 = tid & 63;
    int grp = tid >> 6;              // 0..3

    #pragma unroll
    for (int k = 0; k < 16; ++k) {
        int d = grp + (k << 2);
        float v = pts[(((size_t)((b << 6) + d)) << 12) + n0 + lane6];
        tr[d * 65 + lane6] = v;
    }
    __syncthreads();
    int c = lane6;
    float s = 0.0f, s2 = 0.0f;
    #pragma unroll
    for (int k = 0; k < 16; ++k) {
        int p = grp + (k << 2);
        float v = tr[c * 65 + p];
        P0[((size_t)((b << 12) + n0 + p)) * 64 + c] = v;
        s += v; s2 += v * v;
    }
    slotA[grp * 64 + c] = s;
    slotB[grp * 64 + c] = s2;
    __syncthreads();
    if (tid < 64) {
        float t = slotA[tid] + slotA[64 + tid] + slotA[128 + tid] + slotA[192 + tid];
        atomicAdd(&stats0[rep * 128 + tid], t);
    } else if (tid < 128) {
        int cc = tid - 64;
        float t = slotB[cc] + slotB[64 + cc] + slotB[128 + cc] + slotB[192 + cc];
        atomicAdd(&stats0[rep * 128 + 64 + cc], t);
    }
}

// ---------------------------------------------------------------------------
// Kernel 2: brute-force 8-NN — EXACT R5 form (verified, 111-114 us).
// Scalar-fetch: chunk base wave-uniform via readfirstlane -> s_load;
// no LDS candidate staging. Exactness: chunk c scans contiguous
// [1024c,1024c+1024) ascending; keys unique (idx in low 12 mantissa
// bits, order-preserving, ties->lower idx); d2 formula matches numpy
// bit-for-bit (contract off); gate d2<(float)k7 exact.
// Grid: 8 b x 32 q-tiles of 128 = 256 WGs, 512 threads.
// ---------------------------------------------------------------------------
#define INS(KEY) do { \
    double key = (KEY); \
    double n0 = fmin(k0, key); \
    double n1 = fmin(k1, fmax(k0, key)); \
    double n2 = fmin(k2, fmax(k1, key)); \
    double n3 = fmin(k3, fmax(k2, key)); \
    double n4 = fmin(k4, fmax(k3, key)); \
    double n5 = fmin(k5, fmax(k4, key)); \
    double n6 = fmin(k6, fmax(k5, key)); \
    double n7 = fmin(k7, fmax(k6, key)); \
    k0 = n0; k1 = n1; k2 = n2; k3 = n3; \
    k4 = n4; k5 = n5; k6 = n6; k7 = n7; } while (0)

__global__ __launch_bounds__(512) void knn_kernel(
        const float4* __restrict__ pts4g, int* __restrict__ idx) {
#pragma clang fp contract(off)
    __shared__ double stash[4 * 9 * 128];            // 36 KB (no cand staging)
    int wg = blockIdx.x;
    int b = wg >> 5;
    int q0 = (wg & 31) << 7;
    int tid = threadIdx.x;                           // 0..511

    int lane  = tid & 63;
    int wave  = tid >> 6;            // 0..7
    int chunk = wave & 3;
    int qgrp  = wave >> 2;           // 0..1
    int q_l   = (qgrp << 6) | lane;  // 0..127

    const float4* cb = pts4g + ((size_t)b << 12);
    float4 qp = cb[q0 + q_l];

    double k0, k1, k2, k3, k4, k5, k6, k7;
    k0 = k1 = k2 = k3 = k4 = k5 = k6 = k7 = __builtin_inf();
    float bd7f = 3.4e38f;

    int chu = __builtin_amdgcn_readfirstlane(chunk);
    const float4* cc = cb + ((size_t)chu << 10);     // this wave's 1024-cand window
    int jg0 = chu << 10;                             // global candidate index base

    // --- direct phase: first 128 candidates of the chunk, unconditional ---
    for (int jo = 0; jo < 128; jo += 8) {
        float d2v[8];
        #pragma unroll
        for (int u = 0; u < 8; ++u) {
            float4 p = cc[jo + u];                   // uniform -> s_load
            float dot = (qp.x * p.x + qp.y * p.y) + qp.z * p.z;
            d2v[u] = (qp.w - 2.0f * dot) + p.w;
        }
        #pragma unroll
        for (int u = 0; u < 8; ++u) {
            unsigned long long kb =
                __double_as_longlong((double)d2v[u]) |
                (unsigned long long)(jg0 + jo + u);
            INS(__longlong_as_double(kb));
        }
    }
    bd7f = (float)k7;    // exact: idx bits << half-ulp of f32

    // --- queued phase: branchless hitmask + wave drain ---
    for (int jo = 128; jo < 1024; jo += 8) {
        float d2v[8];
        unsigned hm = 0u;
        #pragma unroll
        for (int u = 0; u < 8; ++u) {
            float4 p = cc[jo + u];                   // uniform -> s_load
            float dot = (qp.x * p.x + qp.y * p.y) + qp.z * p.z;
            float d2 = (qp.w - 2.0f * dot) + p.w;
            d2v[u] = d2;
            hm |= (d2 < bd7f) ? (1u << u) : 0u;
        }
        while (__any(hm != 0u)) {
            if (hm) {
                int u = __builtin_ctz(hm);
                hm &= hm - 1u;
                // cndmask tree: d2 = d2v[u] with static indexing only
                float t0 = (u & 1) ? d2v[1] : d2v[0];
                float t1 = (u & 1) ? d2v[3] : d2v[2];
                float t2 = (u & 1) ? d2v[5] : d2v[4];
                float t3 = (u & 1) ? d2v[7] : d2v[6];
                float s0 = (u & 2) ? t1 : t0;
                float s1 = (u & 2) ? t3 : t2;
                float d2 = (u & 4) ? s1 : s0;
                unsigned long long kb =
                    __double_as_longlong((double)d2) |
                    (unsigned long long)(jg0 + jo + u);
                INS(__longlong_as_double(kb));
            }
        }
        bd7f = (float)k7;
    }

    {
        double* S = &stash[(chunk * 9) * 128 + q_l];
        S[0 * 128] = k0; S[1 * 128] = k1; S[2 * 128] = k2; S[3 * 128] = k3;
        S[4 * 128] = k4; S[5 * 128] = k5; S[6 * 128] = k6; S[7 * 128] = k7;
        S[8 * 128] = __builtin_inf();    // merge guard
    }
    __syncthreads();

    // 4-way merge per query by key (threads 0..127)
    if (tid < 128) {
        int h0 = 0, h1 = 0, h2 = 0, h3 = 0;
        int* op = idx + ((size_t)(b * NPTS + q0 + tid)) * 8;
        #pragma unroll
        for (int t = 0; t < 8; ++t) {
            double b0 = stash[(0 * 9 + h0) * 128 + tid];
            double b1 = stash[(1 * 9 + h1) * 128 + tid];
            double b2 = stash[(2 * 9 + h2) * 128 + tid];
            double b3 = stash[(3 * 9 + h3) * 128 + tid];
            double best = b0; int bc = 0;
            if (b1 < best) { best = b1; bc = 1; }
            if (b2 < best) { best = b2; bc = 2; }
            if (b3 < best) { best = b3; bc = 3; }
            h0 += (bc == 0); h1 += (bc == 1);
            h2 += (bc == 2); h3 += (bc == 3);
            op[t] = (int)(__double_as_longlong(best) & 0xFFFULL);
        }
    }
}

// ---------------------------------------------------------------------------
// Kernel 3 (x12): one residual block — verified R1 form with ONE change:
// the gather's mt stores. Old: 16 b32 stores/thread to mt[(c4+j)*68+pt],
// bank = (272cq+...)%32 -> 16 lanes on 2 banks = 8-way conflict (measured
// 590K conflicts/block in R6's fused run). New: the thread's 4x4
// (point x channel) tile is accumulated in registers, then stored as
// 4 transposed b128 writes to the SAME addresses/stride (b128 floor,
// ~5.6x fewer conflict-cycles). mt contents identical -> GEMM and all
// downstream numerics bit-exact vs the verified kernel.
// Grid: 512 WGs (64 tiles x 8 b, XCD-affine b = wg & 7), 256 threads.
// LDS ~54 KB -> 2 WG/CU.
// ---------------------------------------------------------------------------
__global__ __launch_bounds__(256) void block_kernel(
        const float* __restrict__ Pin, float* __restrict__ Pout,
        const float* __restrict__ statsIn, float* __restrict__ statsOut,
        const float* __restrict__ Wp, const float* __restrict__ Bp,
        const float* __restrict__ Gp, const float* __restrict__ Betap,
        const int* __restrict__ gidx, float* __restrict__ dout, int last) {
    __shared__ __align__(16) float Wt[64 * 68];      // W transposed: Wt[d][o]
    __shared__ __align__(16) float mt[64 * 68];      // m[d][pt]
    __shared__ __align__(16) float selft[64 * 64];   // raw self rows [pt][c]
    __shared__ __align__(16) int   idxl[64 * 8];
    __shared__ __align__(16) float scale_l[64], shift_l[64], bias_l[64];
    __shared__ float slot[4 * 128];

    int wg = blockIdx.x;
    int b = wg & 7;                  // XCD affinity
    int n0 = (wg >> 3) << 6;
    int rep = (wg >> 3) & (NREP - 1);
    int tid = threadIdx.x;

    const float* Pb = Pin + (((size_t)b) << 18);     // batch slice [4096][64]

    // --- setup: idx tile, self tile, W^T, BN affine (replica-summed) ---
    if (tid < 128) {
        ((int4*)idxl)[tid] = ((const int4*)(gidx + ((size_t)(b * NPTS + n0)) * 8))[tid];
    }
    #pragma unroll
    for (int k = 0; k < 4; ++k) {    // self rows: 64 pts x 64 ch, coalesced
        int lin = tid + (k << 8);    // float4 id
        ((float4*)selft)[lin] = ((const float4*)&Pb[(size_t)n0 << 6])[lin];
    }
    #pragma unroll
    for (int k = 0; k < 16; ++k) {
        int lin = tid + (k << 8);
        int o = lin >> 6, d = lin & 63;
        Wt[d * 68 + o] = Wp[lin];
    }
    if (tid < 64) {
        int c = tid;
        float sum = 0.0f, sumsq = 0.0f;
        #pragma unroll
        for (int r = 0; r < NREP; ++r) {
            sum   += statsIn[r * 128 + c];
            sumsq += statsIn[r * 128 + 64 + c];
        }
        float mean = sum * (1.0f / 32768.0f);
        float var  = sumsq * (1.0f / 32768.0f) - mean * mean;
        float rs   = 1.0f / sqrtf(var + 1e-5f);
        float sc   = Gp[c] * rs;
        scale_l[c] = sc;
        shift_l[c] = Betap[c] - mean * sc;
        bias_l[c]  = Bp[c];
    }
    __syncthreads();

    // --- gather: 4x4 register tile, then 4 transposed b128 stores ---
    {
        int cq = tid & 15;           // channel quad: channels 4cq..4cq+3
        int pg = tid >> 4;           // 0..15: points 4pg..4pg+3
        int c4 = cq << 2;
        float4 sc4 = *(const float4*)&scale_l[c4];
        float4 sh4 = *(const float4*)&shift_l[c4];
        float4 r[4];
        #pragma unroll
        for (int i = 0; i < 4; ++i) {
            int pt = (pg << 2) + i;
            int4 ja = *(const int4*)&idxl[pt * 8];
            int4 jb = *(const int4*)&idxl[pt * 8 + 4];
            float4 v[9];
            v[0] = *(const float4*)&selft[(pt << 6) + c4];
            v[1] = *(const float4*)&Pb[(((size_t)ja.x) << 6) + c4];
            v[2] = *(const float4*)&Pb[(((size_t)ja.y) << 6) + c4];
            v[3] = *(const float4*)&Pb[(((size_t)ja.z) << 6) + c4];
            v[4] = *(const float4*)&Pb[(((size_t)ja.w) << 6) + c4];
            v[5] = *(const float4*)&Pb[(((size_t)jb.x) << 6) + c4];
            v[6] = *(const float4*)&Pb[(((size_t)jb.y) << 6) + c4];
            v[7] = *(const float4*)&Pb[(((size_t)jb.z) << 6) + c4];
            v[8] = *(const float4*)&Pb[(((size_t)jb.w) << 6) + c4];
            float4 a = make_float4(0.f, 0.f, 0.f, 0.f);
            #pragma unroll
            for (int k = 0; k < 9; ++k) {
                float hx = v[k].x * sc4.x + sh4.x;
                float hy = v[k].y * sc4.y + sh4.y;
                float hz = v[k].z * sc4.z + sh4.z;
                float hw = v[k].w * sc4.w + sh4.w;
                a.x += fmaxf(hx, 0.01f * hx);
                a.y += fmaxf(hy, 0.01f * hy);
                a.z += fmaxf(hz, 0.01f * hz);
                a.w += fmaxf(hw, 0.01f * hw);
            }
            r[i] = make_float4(a.x * (1.0f / 9.0f), a.y * (1.0f / 9.0f),
                               a.z * (1.0f / 9.0f), a.w * (1.0f / 9.0f));
        }
        int pb4 = pg << 2;
        *(float4*)&mt[(c4 + 0) * 68 + pb4] = make_float4(r[0].x, r[1].x, r[2].x, r[3].x);
        *(float4*)&mt[(c4 + 1) * 68 + pb4] = make_float4(r[0].y, r[1].y, r[2].y, r[3].y);
        *(float4*)&mt[(c4 + 2) * 68 + pb4] = make_float4(r[0].z, r[1].z, r[2].z, r[3].z);
        *(float4*)&mt[(c4 + 3) * 68 + pb4] = make_float4(r[0].w, r[1].w, r[2].w, r[3].w);
    }
    __syncthreads();

    // --- GEMM: out[pt][o] = sum_d Wt[d][o] * m[d][pt] + bias[o] ---
    int o0 = (tid & 15) << 2;
    int p0 = (tid >> 4) << 2;
    float4 acc[4];
    {
        float4 bias4 = *(const float4*)&bias_l[o0];
        acc[0] = bias4; acc[1] = bias4; acc[2] = bias4; acc[3] = bias4;
    }
    #pragma unroll
    for (int d = 0; d < 64; ++d) {
        float4 wv = *(const float4*)&Wt[d * 68 + o0];
        float4 a  = *(const float4*)&mt[d * 68 + p0];
        acc[0].x += wv.x * a.x; acc[0].y += wv.y * a.x; acc[0].z += wv.z * a.x; acc[0].w += wv.w * a.x;
        acc[1].x += wv.x * a.y; acc[1].y += wv.y * a.y; acc[1].z += wv.z * a.y; acc[1].w += wv.w * a.y;
        acc[2].x += wv.x * a.z; acc[2].y += wv.y * a.z; acc[2].z += wv.z * a.z; acc[2].w += wv.w * a.z;
        acc[3].x += wv.x * a.w; acc[3].y += wv.y * a.w; acc[3].z += wv.z * a.w; acc[3].w += wv.w * a.w;
    }

    // --- residual add (self rows from LDS) ---
    #pragma unroll
    for (int j = 0; j < 4; ++j) {
        float4 r = *(const float4*)&selft[((p0 + j) << 6) + o0];
        acc[j].x += r.x; acc[j].y += r.y; acc[j].z += r.z; acc[j].w += r.w;
    }

    if (!last) {
        float* PbOut = Pout + ((((size_t)b) << 12) + n0) * 64;
        #pragma unroll
        for (int j = 0; j < 4; ++j)
            *(float4*)&PbOut[((size_t)(p0 + j)) * 64 + o0] = acc[j];

        float4 s, s2;
        s.x = acc[0].x + acc[1].x + acc[2].x + acc[3].x;
        s.y = acc[0].y + acc[1].y + acc[2].y + acc[3].y;
        s.z = acc[0].z + acc[1].z + acc[2].z + acc[3].z;
        s.w = acc[0].w + acc[1].w + acc[2].w + acc[3].w;
        s2.x = acc[0].x*acc[0].x + acc[1].x*acc[1].x + acc[2].x*acc[2].x + acc[3].x*acc[3].x;
        s2.y = acc[0].y*acc[0].y + acc[1].y*acc[1].y + acc[2].y*acc[2].y + acc[3].y*acc[3].y;
        s2.z = acc[0].z*acc[0].z + acc[1].z*acc[1].z + acc[2].z*acc[2].z + acc[3].z*acc[3].z;
        s2.w = acc[0].w*acc[0].w + acc[1].w*acc[1].w + acc[2].w*acc[2].w + acc[3].w*acc[3].w;
        #pragma unroll
        for (int m = 16; m <= 32; m <<= 1) {
            s.x += __shfl_xor(s.x, m, 64);  s.y += __shfl_xor(s.y, m, 64);
            s.z += __shfl_xor(s.z, m, 64);  s.w += __shfl_xor(s.w, m, 64);
            s2.x += __shfl_xor(s2.x, m, 64); s2.y += __shfl_xor(s2.y, m, 64);
            s2.z += __shfl_xor(s2.z, m, 64); s2.w += __shfl_xor(s2.w, m, 64);
        }
        if ((tid & 63) < 16) {
            int w = tid >> 6;
            slot[w * 128 + o0 + 0] = s.x;  slot[w * 128 + o0 + 1] = s.y;
            slot[w * 128 + o0 + 2] = s.z;  slot[w * 128 + o0 + 3] = s.w;
            slot[w * 128 + 64 + o0 + 0] = s2.x; slot[w * 128 + 64 + o0 + 1] = s2.y;
            slot[w * 128 + 64 + o0 + 2] = s2.z; slot[w * 128 + 64 + o0 + 3] = s2.w;
        }
        __syncthreads();
        if (tid < 128) {
            float t = slot[tid] + slot[128 + tid] + slot[256 + tid] + slot[384 + tid];
            atomicAdd(&statsOut[rep * 128 + tid], t);
        }
    } else {
        __syncthreads();                         // all mt reads done
        float* stage = mt;                       // reuse as [o][pt], 16 KB
        #pragma unroll
        for (int j = 0; j < 4; ++j) {
            stage[(o0 + 0) * 64 + p0 + j] = acc[j].x;
            stage[(o0 + 1) * 64 + p0 + j] = acc[j].y;
            stage[(o0 + 2) * 64 + p0 + j] = acc[j].z;
            stage[(o0 + 3) * 64 + p0 + j] = acc[j].w;
        }
        __syncthreads();
        #pragma unroll
        for (int k = 0; k < 16; ++k) {
            int lin = tid + (k << 8);
            int o = lin >> 6, pt = lin & 63;
            dout[(((size_t)((b << 6) + o)) << 12) + n0 + pt] = stage[lin];
        }
    }
}

// ---------------------------------------------------------------------------
extern "C" void kernel_launch(void* const* d_in, const int* in_sizes, int n_in,
                              void* d_out, int out_size, void* d_ws, size_t ws_size,
                              hipStream_t stream) {
    const float* xyz    = (const float*)d_in[0];
    const float* pts    = (const float*)d_in[1];
    const float* conv_w = (const float*)d_in[2];
    const float* conv_b = (const float*)d_in[3];
    const float* gamma  = (const float*)d_in[4];
    const float* beta   = (const float*)d_in[5];
    float* out = (float*)d_out;

    char* ws = (char*)d_ws;
    float*  P0    = (float*)(ws);                                  //  8 MB
    float*  P1    = (float*)(ws + (size_t)8 * 1024 * 1024);        //  8 MB
    int*    idx   = (int*)  (ws + (size_t)16 * 1024 * 1024);       //  1 MB
    float*  stats = (float*)(ws + (size_t)17 * 1024 * 1024);       // 52 KB
    float4* pts4g = (float4*)(ws + (size_t)18 * 1024 * 1024);      // 512 KB

    prep_kernel<<<128, 256, 0, stream>>>(xyz, pts4g, stats);
    cast_kernel<<<512, 256, 0, stream>>>(pts, P0, stats);
    knn_kernel<<<256, 512, 0, stream>>>(pts4g, idx);

    float* Pbuf[2] = {P0, P1};
    for (int t = 0; t < NBLK; ++t) {
        block_kernel<<<512, 256, 0, stream>>>(
            Pbuf[t & 1], Pbuf[(t + 1) & 1],
            stats + (size_t)t * NREP * 128, stats + (size_t)(t + 1) * NREP * 128,
            conv_w + (size_t)t * 4096, conv_b + (size_t)t * 64,
            gamma + (size_t)t * 64, beta + (size_t)t * 64,
            idx, out, (t == NBLK - 1) ? 1 : 0);
    }
}

// Round 9
// 284.806 us; speedup vs baseline: 2.9621x; 1.0854x over previous
//
#include <hip/hip_runtime.h>
#include <hip/hip_bf16.h>

// Problem constants
#define NB     8
#define NPTS   4096
#define DIMC   64
#define KNN_K  8
#define NBLK   12
#define NREP   8      // stats replicas (atomic de-contention)

typedef __attribute__((ext_vector_type(8))) short short8;   // 8 bf16 = 4 VGPR
typedef __attribute__((ext_vector_type(4))) float f32x4;    // MFMA acc

// Dekker split: v = hi + lo with hi = bf16-truncate(v); v - hi is EXACT in
// fp32 (Sterbenz: hi has v's sign/exponent, |v-hi| < ulp_bf16(v)); lo is the
// bf16-truncation of the remainder. Combined precision ~16 mantissa bits.
__device__ __forceinline__ void bsplit(float v, unsigned short& h, unsigned short& l) {
    unsigned b = __float_as_uint(v);
    h = (unsigned short)(b >> 16);
    float hf = __uint_as_float(b & 0xFFFF0000u);
    float lf = v - hf;                       // exact
    l = (unsigned short)(__float_as_uint(lf) >> 16);
}

// ---------------------------------------------------------------------------
// Kernel 0: precompute (x, y, z, |x|^2) per point for the KNN kernel,
// PLUS zero all 13 stats stages. sq formula matches numpy bit-for-bit.
// ---------------------------------------------------------------------------
__global__ __launch_bounds__(256) void prep_kernel(
        const float* __restrict__ xyz, float4* __restrict__ pts4g,
        float* __restrict__ stats) {
#pragma clang fp contract(off)
    int g = blockIdx.x * 256 + threadIdx.x;      // 0..32767
    if (g < 13 * NREP * 128) stats[g] = 0.0f;
    int b = g >> 12, j = g & 4095;
    const float* xb = xyz + (size_t)b * 3 * NPTS;
    float x = xb[j];
    float y = xb[NPTS + j];
    float z = xb[2 * NPTS + j];
    float sq = (x * x + y * y) + z * z;
    pts4g[g] = make_float4(x, y, z, sq);
}

// ---------------------------------------------------------------------------
// Kernel 1: transpose fp32 points [b][d][n] -> point-major P0[b][n][d],
// fused with stats[0] accumulation. XCD-affine: b = blockIdx & 7.
// Grid: 512 WGs, 256 threads.
// ---------------------------------------------------------------------------
__global__ __launch_bounds__(256) void cast_kernel(
        const float* __restrict__ pts,
        float* __restrict__ P0, float* __restrict__ stats0) {
    __shared__ __align__(16) float tr[64 * 65];      // [d][n] transpose tile (+1 pad)
    __shared__ float slotA[4 * 64], slotB[4 * 64];
    int wg = blockIdx.x;
    int b = wg & 7;                  // XCD affinity
    int n0 = (wg >> 3) << 6;
    int rep = (wg >> 3) & (NREP - 1);
    int tid = threadIdx.x;
    int lane6 = tid & 63;
    int grp = tid >> 6;              // 0..3

    #pragma unroll
    for (int k = 0; k < 16; ++k) {
        int d = grp + (k << 2);
        float v = pts[(((size_t)((b << 6) + d)) << 12) + n0 + lane6];
        tr[d * 65 + lane6] = v;
    }
    __syncthreads();
    int c = lane6;
    float s = 0.0f, s2 = 0.0f;
    #pragma unroll
    for (int k = 0; k < 16; ++k) {
        int p = grp + (k << 2);
        float v = tr[c * 65 + p];
        P0[((size_t)((b << 12) + n0 + p)) * 64 + c] = v;
        s += v; s2 += v * v;
    }
    slotA[grp * 64 + c] = s;
    slotB[grp * 64 + c] = s2;
    __syncthreads();
    if (tid < 64) {
        float t = slotA[tid] + slotA[64 + tid] + slotA[128 + tid] + slotA[192 + tid];
        atomicAdd(&stats0[rep * 128 + tid], t);
    } else if (tid < 128) {
        int cc = tid - 64;
        float t = slotB[cc] + slotB[64 + cc] + slotB[128 + cc] + slotB[192 + cc];
        atomicAdd(&stats0[rep * 128 + 64 + cc], t);
    }
}

// ---------------------------------------------------------------------------
// Kernel 2: brute-force 8-NN — EXACT R5 form (verified, 111-114 us).
// Scalar-fetch via readfirstlane; no LDS candidate staging; bit-exact d2;
// unique f64 keys (idx in low 12 mantissa bits).
// Grid: 8 b x 32 q-tiles of 128 = 256 WGs, 512 threads.
// ---------------------------------------------------------------------------
#define INS(KEY) do { \
    double key = (KEY); \
    double n0 = fmin(k0, key); \
    double n1 = fmin(k1, fmax(k0, key)); \
    double n2 = fmin(k2, fmax(k1, key)); \
    double n3 = fmin(k3, fmax(k2, key)); \
    double n4 = fmin(k4, fmax(k3, key)); \
    double n5 = fmin(k5, fmax(k4, key)); \
    double n6 = fmin(k6, fmax(k5, key)); \
    double n7 = fmin(k7, fmax(k6, key)); \
    k0 = n0; k1 = n1; k2 = n2; k3 = n3; \
    k4 = n4; k5 = n5; k6 = n6; k7 = n7; } while (0)

__global__ __launch_bounds__(512) void knn_kernel(
        const float4* __restrict__ pts4g, int* __restrict__ idx) {
#pragma clang fp contract(off)
    __shared__ double stash[4 * 9 * 128];            // 36 KB
    int wg = blockIdx.x;
    int b = wg >> 5;
    int q0 = (wg & 31) << 7;
    int tid = threadIdx.x;                           // 0..511

    int lane  = tid & 63;
    int wave  = tid >> 6;            // 0..7
    int chunk = wave & 3;
    int qgrp  = wave >> 2;           // 0..1
    int q_l   = (qgrp << 6) | lane;  // 0..127

    const float4* cb = pts4g + ((size_t)b << 12);
    float4 qp = cb[q0 + q_l];

    double k0, k1, k2, k3, k4, k5, k6, k7;
    k0 = k1 = k2 = k3 = k4 = k5 = k6 = k7 = __builtin_inf();
    float bd7f = 3.4e38f;

    int chu = __builtin_amdgcn_readfirstlane(chunk);
    const float4* cc = cb + ((size_t)chu << 10);     // this wave's 1024-cand window
    int jg0 = chu << 10;                             // global candidate index base

    // --- direct phase: first 128 candidates of the chunk, unconditional ---
    for (int jo = 0; jo < 128; jo += 8) {
        float d2v[8];
        #pragma unroll
        for (int u = 0; u < 8; ++u) {
            float4 p = cc[jo + u];                   // uniform -> s_load
            float dot = (qp.x * p.x + qp.y * p.y) + qp.z * p.z;
            d2v[u] = (qp.w - 2.0f * dot) + p.w;
        }
        #pragma unroll
        for (int u = 0; u < 8; ++u) {
            unsigned long long kb =
                __double_as_longlong((double)d2v[u]) |
                (unsigned long long)(jg0 + jo + u);
            INS(__longlong_as_double(kb));
        }
    }
    bd7f = (float)k7;    // exact: idx bits << half-ulp of f32

    // --- queued phase: branchless hitmask + wave drain ---
    for (int jo = 128; jo < 1024; jo += 8) {
        float d2v[8];
        unsigned hm = 0u;
        #pragma unroll
        for (int u = 0; u < 8; ++u) {
            float4 p = cc[jo + u];                   // uniform -> s_load
            float dot = (qp.x * p.x + qp.y * p.y) + qp.z * p.z;
            float d2 = (qp.w - 2.0f * dot) + p.w;
            d2v[u] = d2;
            hm |= (d2 < bd7f) ? (1u << u) : 0u;
        }
        while (__any(hm != 0u)) {
            if (hm) {
                int u = __builtin_ctz(hm);
                hm &= hm - 1u;
                float t0 = (u & 1) ? d2v[1] : d2v[0];
                float t1 = (u & 1) ? d2v[3] : d2v[2];
                float t2 = (u & 1) ? d2v[5] : d2v[4];
                float t3 = (u & 1) ? d2v[7] : d2v[6];
                float s0 = (u & 2) ? t1 : t0;
                float s1 = (u & 2) ? t3 : t2;
                float d2 = (u & 4) ? s1 : s0;
                unsigned long long kb =
                    __double_as_longlong((double)d2) |
                    (unsigned long long)(jg0 + jo + u);
                INS(__longlong_as_double(kb));
            }
        }
        bd7f = (float)k7;
    }

    {
        double* S = &stash[(chunk * 9) * 128 + q_l];
        S[0 * 128] = k0; S[1 * 128] = k1; S[2 * 128] = k2; S[3 * 128] = k3;
        S[4 * 128] = k4; S[5 * 128] = k5; S[6 * 128] = k6; S[7 * 128] = k7;
        S[8 * 128] = __builtin_inf();    // merge guard
    }
    __syncthreads();

    // 4-way merge per query by key (threads 0..127)
    if (tid < 128) {
        int h0 = 0, h1 = 0, h2 = 0, h3 = 0;
        int* op = idx + ((size_t)(b * NPTS + q0 + tid)) * 8;
        #pragma unroll
        for (int t = 0; t < 8; ++t) {
            double b0 = stash[(0 * 9 + h0) * 128 + tid];
            double b1 = stash[(1 * 9 + h1) * 128 + tid];
            double b2 = stash[(2 * 9 + h2) * 128 + tid];
            double b3 = stash[(3 * 9 + h3) * 128 + tid];
            double best = b0; int bc = 0;
            if (b1 < best) { best = b1; bc = 1; }
            if (b2 < best) { best = b2; bc = 2; }
            if (b3 < best) { best = b3; bc = 3; }
            h0 += (bc == 0); h1 += (bc == 1);
            h2 += (bc == 2); h3 += (bc == 3);
            op[t] = (int)(__double_as_longlong(best) & 0xFFFULL);
        }
    }
}

// ---------------------------------------------------------------------------
// Kernel 3 (x12): one residual block. GEMM moved to MFMA (split-bf16):
//   - m and W stored as hi/lo bf16 planes (Dekker split; 3 MFMA products
//     hi*hi + hi*lo + lo*hi, fp32 accumulate -> rel err ~3e-5, final
//     output error <0.01 vs 0.186 threshold).
//   - m layout [pt][d] (gather's NATURAL orientation, transpose deleted);
//     W layout [o][d] (conv_w's original layout, staging transpose
//     deleted). Both stride 72 bf16 (2-way b128 floor).
//   - mfma_f32_16x16x32_bf16; D mapping col=lane&15, row=4*(lane>>4)+reg
//     (HW-verified). A row = lane&15, B col = lane&15; the k-slot order
//     cancels because A and B use the SAME k-bijection (slot-paired sum).
//   - per-thread LDS reads 128 -> 20 b128; GEMM VALU -> 24 MFMA/wave.
// Everything else (gather, stats replicas, XCD affinity) = verified R8.
// Grid: 512 WGs (64 tiles x 8 b), 256 threads. LDS ~58 KB -> 2 WG/CU.
// ---------------------------------------------------------------------------
#define AH_OFF 0
#define AL_OFF (64 * 72)
#define WH_OFF (2 * 64 * 72)
#define WL_OFF (3 * 64 * 72)

__global__ __launch_bounds__(256) void block_kernel(
        const float* __restrict__ Pin, float* __restrict__ Pout,
        const float* __restrict__ statsIn, float* __restrict__ statsOut,
        const float* __restrict__ Wp, const float* __restrict__ Bp,
        const float* __restrict__ Gp, const float* __restrict__ Betap,
        const int* __restrict__ gidx, float* __restrict__ dout, int last) {
    __shared__ __align__(16) unsigned short planes[4 * 64 * 72]; // Ah|Al|Wh|Wl, 36 KB
    __shared__ __align__(16) float selft[64 * 64];   // raw self rows [pt][c]
    __shared__ __align__(16) int   idxl[64 * 8];
    __shared__ __align__(16) float scale_l[64], shift_l[64], bias_l[64];
    __shared__ float slot[4 * 128];

    int wg = blockIdx.x;
    int b = wg & 7;                  // XCD affinity
    int n0 = (wg >> 3) << 6;
    int rep = (wg >> 3) & (NREP - 1);
    int tid = threadIdx.x;

    const float* Pb = Pin + (((size_t)b) << 18);     // batch slice [4096][64]

    // --- setup: idx tile, self tile, W hi/lo planes, BN affine ---
    if (tid < 128) {
        ((int4*)idxl)[tid] = ((const int4*)(gidx + ((size_t)(b * NPTS + n0)) * 8))[tid];
    }
    #pragma unroll
    for (int k = 0; k < 4; ++k) {    // self rows: 64 pts x 64 ch, coalesced
        int lin = tid + (k << 8);    // float4 id
        ((float4*)selft)[lin] = ((const float4*)&Pb[(size_t)n0 << 6])[lin];
    }
    #pragma unroll
    for (int k = 0; k < 4; ++k) {    // W: 1024 float4 reads, split to bf16 planes
        int lin = tid + (k << 8);    // 0..1023
        float4 wv = ((const float4*)Wp)[lin];
        int o = lin >> 4, d4 = (lin & 15) << 2;
        unsigned short hx, hy, hz, hw, lx, ly, lz, lw;
        bsplit(wv.x, hx, lx); bsplit(wv.y, hy, ly);
        bsplit(wv.z, hz, lz); bsplit(wv.w, hw, lw);
        *(ushort4*)&planes[WH_OFF + o * 72 + d4] = make_ushort4(hx, hy, hz, hw);
        *(ushort4*)&planes[WL_OFF + o * 72 + d4] = make_ushort4(lx, ly, lz, lw);
    }
    if (tid < 64) {
        int c = tid;
        float sum = 0.0f, sumsq = 0.0f;
        #pragma unroll
        for (int r = 0; r < NREP; ++r) {
            sum   += statsIn[r * 128 + c];
            sumsq += statsIn[r * 128 + 64 + c];
        }
        float mean = sum * (1.0f / 32768.0f);
        float var  = sumsq * (1.0f / 32768.0f) - mean * mean;
        float rs   = 1.0f / sqrtf(var + 1e-5f);
        float sc   = Gp[c] * rs;
        scale_l[c] = sc;
        shift_l[c] = Betap[c] - mean * sc;
        bias_l[c]  = Bp[c];
    }
    __syncthreads();

    // --- gather: m[pt][c4..c4+3] -> hi/lo bf16 planes (natural layout) ---
    {
        int cq = tid & 15;           // channel quad: channels 4cq..4cq+3
        int pg = tid >> 4;           // 0..15: points 4pg..4pg+3
        int c4 = cq << 2;
        float4 sc4 = *(const float4*)&scale_l[c4];
        float4 sh4 = *(const float4*)&shift_l[c4];
        #pragma unroll
        for (int i = 0; i < 4; ++i) {
            int pt = (pg << 2) + i;
            int4 ja = *(const int4*)&idxl[pt * 8];
            int4 jb = *(const int4*)&idxl[pt * 8 + 4];
            float4 v[9];
            v[0] = *(const float4*)&selft[(pt << 6) + c4];
            v[1] = *(const float4*)&Pb[(((size_t)ja.x) << 6) + c4];
            v[2] = *(const float4*)&Pb[(((size_t)ja.y) << 6) + c4];
            v[3] = *(const float4*)&Pb[(((size_t)ja.z) << 6) + c4];
            v[4] = *(const float4*)&Pb[(((size_t)ja.w) << 6) + c4];
            v[5] = *(const float4*)&Pb[(((size_t)jb.x) << 6) + c4];
            v[6] = *(const float4*)&Pb[(((size_t)jb.y) << 6) + c4];
            v[7] = *(const float4*)&Pb[(((size_t)jb.z) << 6) + c4];
            v[8] = *(const float4*)&Pb[(((size_t)jb.w) << 6) + c4];
            float4 a = make_float4(0.f, 0.f, 0.f, 0.f);
            #pragma unroll
            for (int k = 0; k < 9; ++k) {
                float hx = v[k].x * sc4.x + sh4.x;
                float hy = v[k].y * sc4.y + sh4.y;
                float hz = v[k].z * sc4.z + sh4.z;
                float hw = v[k].w * sc4.w + sh4.w;
                a.x += fmaxf(hx, 0.01f * hx);
                a.y += fmaxf(hy, 0.01f * hy);
                a.z += fmaxf(hz, 0.01f * hz);
                a.w += fmaxf(hw, 0.01f * hw);
            }
            float mx = a.x * (1.0f / 9.0f), my = a.y * (1.0f / 9.0f);
            float mz = a.z * (1.0f / 9.0f), mw = a.w * (1.0f / 9.0f);
            unsigned short hx2, hy2, hz2, hw2, lx2, ly2, lz2, lw2;
            bsplit(mx, hx2, lx2); bsplit(my, hy2, ly2);
            bsplit(mz, hz2, lz2); bsplit(mw, hw2, lw2);
            *(ushort4*)&planes[AH_OFF + pt * 72 + c4] = make_ushort4(hx2, hy2, hz2, hw2);
            *(ushort4*)&planes[AL_OFF + pt * 72 + c4] = make_ushort4(lx2, ly2, lz2, lw2);
        }
    }
    __syncthreads();

    // --- GEMM via MFMA: wave w -> pt rows [16w,16w+16), all 64 o ---
    int lane = tid & 63;
    int w    = tid >> 6;             // 0..3
    int g    = lane >> 4;            // k-group
    int c    = lane & 15;
    int ptb  = w << 4;

    short8 a_h[2], a_l[2];
    #pragma unroll
    for (int s = 0; s < 2; ++s) {
        int off = (ptb + c) * 72 + (s << 5) + (g << 3);
        a_h[s] = *(const short8*)&planes[AH_OFF + off];
        a_l[s] = *(const short8*)&planes[AL_OFF + off];
    }

    f32x4 out[4];
    #pragma unroll
    for (int ot = 0; ot < 4; ++ot) {
        int co = (ot << 4) + c;
        short8 b_h[2], b_l[2];
        #pragma unroll
        for (int s = 0; s < 2; ++s) {
            int off = co * 72 + (s << 5) + (g << 3);
            b_h[s] = *(const short8*)&planes[WH_OFF + off];
            b_l[s] = *(const short8*)&planes[WL_OFF + off];
        }
        f32x4 acc = {0.f, 0.f, 0.f, 0.f};
        acc = __builtin_amdgcn_mfma_f32_16x16x32_bf16(a_h[0], b_h[0], acc, 0, 0, 0);
        acc = __builtin_amdgcn_mfma_f32_16x16x32_bf16(a_h[1], b_h[1], acc, 0, 0, 0);
        acc = __builtin_amdgcn_mfma_f32_16x16x32_bf16(a_h[0], b_l[0], acc, 0, 0, 0);
        acc = __builtin_amdgcn_mfma_f32_16x16x32_bf16(a_h[1], b_l[1], acc, 0, 0, 0);
        acc = __builtin_amdgcn_mfma_f32_16x16x32_bf16(a_l[0], b_h[0], acc, 0, 0, 0);
        acc = __builtin_amdgcn_mfma_f32_16x16x32_bf16(a_l[1], b_h[1], acc, 0, 0, 0);
        out[ot] = acc;
    }

    // --- epilogue: + bias + residual; D lane holds col=16ot+c, row=4g+j ---
    #pragma unroll
    for (int ot = 0; ot < 4; ++ot) {
        int co = (ot << 4) + c;
        float bv = bias_l[co];
        #pragma unroll
        for (int j = 0; j < 4; ++j) {
            int pt = ptb + (g << 2) + j;
            out[ot][j] += bv + selft[(pt << 6) + co];
        }
    }

    if (!last) {
        float* PbOut = Pout + ((((size_t)b) << 12) + n0) * 64;
        #pragma unroll
        for (int j = 0; j < 4; ++j) {
            int pt = ptb + (g << 2) + j;
            #pragma unroll
            for (int ot = 0; ot < 4; ++ot)
                PbOut[(size_t)pt * 64 + (ot << 4) + c] = out[ot][j];
        }

        // --- stats: j-sum (4 pts) then xor over g -> wave col-sums ---
        float sv[4], qv[4];
        #pragma unroll
        for (int ot = 0; ot < 4; ++ot) {
            float s = 0.f, q = 0.f;
            #pragma unroll
            for (int j = 0; j < 4; ++j) {
                float v = out[ot][j];
                s += v; q += v * v;
            }
            sv[ot] = s; qv[ot] = q;
        }
        #pragma unroll
        for (int m = 16; m <= 32; m <<= 1) {
            #pragma unroll
            for (int ot = 0; ot < 4; ++ot) {
                sv[ot] += __shfl_xor(sv[ot], m, 64);
                qv[ot] += __shfl_xor(qv[ot], m, 64);
            }
        }
        if (lane < 16) {
            #pragma unroll
            for (int ot = 0; ot < 4; ++ot) {
                slot[w * 128 + (ot << 4) + lane]      = sv[ot];
                slot[w * 128 + 64 + (ot << 4) + lane] = qv[ot];
            }
        }
        __syncthreads();
        if (tid < 128) {
            float t = slot[tid] + slot[128 + tid] + slot[256 + tid] + slot[384 + tid];
            atomicAdd(&statsOut[rep * 128 + tid], t);
        }
    } else {
        __syncthreads();                         // all plane reads done
        float* stage = (float*)planes;           // reuse as [o][pt] (65-pad), 16.6 KB
        #pragma unroll
        for (int ot = 0; ot < 4; ++ot) {
            int co = (ot << 4) + c;
            #pragma unroll
            for (int j = 0; j < 4; ++j)
                stage[co * 65 + ptb + (g << 2) + j] = out[ot][j];
        }
        __syncthreads();
        #pragma unroll
        for (int k = 0; k < 16; ++k) {
            int lin = tid + (k << 8);
            int o = lin >> 6, pt = lin & 63;
            dout[(((size_t)((b << 6) + o)) << 12) + n0 + pt] = stage[o * 65 + pt];
        }
    }
}

// ---------------------------------------------------------------------------
extern "C" void kernel_launch(void* const* d_in, const int* in_sizes, int n_in,
                              void* d_out, int out_size, void* d_ws, size_t ws_size,
                              hipStream_t stream) {
    const float* xyz    = (const float*)d_in[0];
    const float* pts    = (const float*)d_in[1];
    const float* conv_w = (const float*)d_in[2];
    const float* conv_b = (const float*)d_in[3];
    const float* gamma  = (const float*)d_in[4];
    const float* beta   = (const float*)d_in[5];
    float* out = (float*)d_out;

    char* ws = (char*)d_ws;
    float*  P0    = (float*)(ws);                                  //  8 MB
    float*  P1    = (float*)(ws + (size_t)8 * 1024 * 1024);        //  8 MB
    int*    idx   = (int*)  (ws + (size_t)16 * 1024 * 1024);       //  1 MB
    float*  stats = (float*)(ws + (size_t)17 * 1024 * 1024);       // 52 KB
    float4* pts4g = (float4*)(ws + (size_t)18 * 1024 * 1024);      // 512 KB

    prep_kernel<<<128, 256, 0, stream>>>(xyz, pts4g, stats);
    cast_kernel<<<512, 256, 0, stream>>>(pts, P0, stats);
    knn_kernel<<<256, 512, 0, stream>>>(pts4g, idx);

    float* Pbuf[2] = {P0, P1};
    for (int t = 0; t < NBLK; ++t) {
        block_kernel<<<512, 256, 0, stream>>>(
            Pbuf[t & 1], Pbuf[(t + 1) & 1],
            stats + (size_t)t * NREP * 128, stats + (size_t)(t + 1) * NREP * 128,
            conv_w + (size_t)t * 4096, conv_b + (size_t)t * 64,
            gamma + (size_t)t * 64, beta + (size_t)t * 64,
            idx, out, (t == NBLK - 1) ? 1 : 0);
    }
}